// Round 1
// baseline (225.042 us; speedup 1.0000x reference)
//
#include <hip/hip_runtime.h>

// Problem constants (fixed by the reference)
constexpr int B_N   = 2048;
constexpr int C_N   = 32;
constexpr int SD    = 64;    // STATE_DIM
constexpr int EMB   = 256;
constexpr int OUTD  = 256;
constexpr int OBSD  = 512;
constexpr int XDIM  = 512;   // concat dim
constexpr int CAP   = 512;   // per-category row capacity (mean 64, 512 is >50 sigma)

// ws layout:
//   [0, 128)            int counts[32]
//   [128, 128+32*CAP*4) int rows[32][CAP]
//   [128K, 128K+4MB)    float x[B][512]   (cols 0..255 = state_emb, 256..511 = obs_emb)

__global__ void bucket_kernel(const int* __restrict__ cat_ids,
                              int* __restrict__ counts,
                              int* __restrict__ rows) {
    int t = blockIdx.x * blockDim.x + threadIdx.x;
    if (t < B_N) {
        int c = cat_ids[t];
        int slot = atomicAdd(&counts[c], 1);
        if (slot < CAP) rows[c * CAP + slot] = t;
    }
}

// 8 batch rows x 128 output cols per block; 256 threads.
// grid.x = (B/8) * 2 ; bid>>1 = row tile, bid&1 = col half.
__global__ __launch_bounds__(256) void embed_kernel(
    const float* __restrict__ state, const float* __restrict__ obs,
    const int* __restrict__ cat_ids,
    const float* __restrict__ obs_W, const float* __restrict__ obs_b,
    const float* __restrict__ state_W, const float* __restrict__ state_b,
    float* __restrict__ x) {
    __shared__ float s_obs[8 * OBSD];   // 16 KB
    __shared__ float s_state[8 * SD];   // 2 KB

    const int bid = blockIdx.x;
    const int bm0 = (bid >> 1) * 8;
    const int colbase = (bid & 1) * 128;
    const int t = threadIdx.x;

    // Stage obs tile: 8*512 = 4096 contiguous floats
    {
        const float4* src = (const float4*)(obs + (size_t)bm0 * OBSD);
        float4* dst = (float4*)s_obs;
        #pragma unroll
        for (int j = 0; j < 4; ++j) dst[t + 256 * j] = src[t + 256 * j];
    }
    // Stage state tile: 8*64 = 512 contiguous floats
    if (t < 128) {
        ((float4*)s_state)[t] = ((const float4*)(state + (size_t)bm0 * SD))[t];
    }
    __syncthreads();

    const int hq = t & 63;          // lane -> 2 columns
    const int rg = t >> 6;          // wave -> 2 rows (wave-uniform)
    const int col = colbase + 2 * hq;
    const int r0 = rg * 2;

    // ---- obs_emb: K=512, shared weights ----
    float o00 = 0.f, o01 = 0.f, o10 = 0.f, o11 = 0.f;
    {
        const float2* wp = (const float2*)obs_W + (col >> 1);
        const float* a0p = s_obs + r0 * OBSD;
        const float* a1p = s_obs + (r0 + 1) * OBSD;
        #pragma unroll 8
        for (int d = 0; d < OBSD; ++d) {
            float2 w = wp[d * 128];
            float a0 = a0p[d];
            float a1 = a1p[d];
            o00 += a0 * w.x; o01 += a0 * w.y;
            o10 += a1 * w.x; o11 += a1 * w.y;
        }
    }

    // ---- state_emb: K=64, per-row category weights ----
    const int g0 = bm0 + r0;
    const int g1 = bm0 + r0 + 1;
    const int c0 = cat_ids[g0];
    const int c1 = cat_ids[g1];
    float s00 = 0.f, s01 = 0.f, s10 = 0.f, s11 = 0.f;
    {
        const float2* w0p = (const float2*)(state_W + (size_t)c0 * SD * EMB) + (col >> 1);
        const float2* w1p = (const float2*)(state_W + (size_t)c1 * SD * EMB) + (col >> 1);
        const float* a0p = s_state + r0 * SD;
        const float* a1p = s_state + (r0 + 1) * SD;
        #pragma unroll 8
        for (int d = 0; d < SD; ++d) {
            float2 w0 = w0p[d * 128];
            float2 w1 = w1p[d * 128];
            float a0 = a0p[d];
            float a1 = a1p[d];
            s00 += a0 * w0.x; s01 += a0 * w0.y;
            s10 += a1 * w1.x; s11 += a1 * w1.y;
        }
    }

    // biases + relu
    s00 = fmaxf(s00 + state_b[c0 * EMB + col], 0.f);
    s01 = fmaxf(s01 + state_b[c0 * EMB + col + 1], 0.f);
    s10 = fmaxf(s10 + state_b[c1 * EMB + col], 0.f);
    s11 = fmaxf(s11 + state_b[c1 * EMB + col + 1], 0.f);
    float ob0 = obs_b[col], ob1 = obs_b[col + 1];
    o00 += ob0; o01 += ob1; o10 += ob0; o11 += ob1;

    // write x: state part at cols [0,256), obs part at [256,512)
    float2* x0 = (float2*)(x + (size_t)g0 * XDIM);
    float2* x1 = (float2*)(x + (size_t)g1 * XDIM);
    x0[col >> 1] = make_float2(s00, s01);
    x0[(EMB + col) >> 1] = make_float2(o00, o01);
    x1[col >> 1] = make_float2(s10, s11);
    x1[(EMB + col) >> 1] = make_float2(o10, o11);
}

// grid: (32 cats, CAP/8 tiles, 2 col halves); 256 threads.
__global__ __launch_bounds__(256) void l2_kernel(
    const float* __restrict__ x, const float* __restrict__ l2_W,
    const float* __restrict__ l2_b, const int* __restrict__ counts,
    const int* __restrict__ rows, float* __restrict__ out) {
    const int c = blockIdx.x;
    const int tile = blockIdx.y;
    const int colbase = blockIdx.z * 128;
    const int n = counts[c];
    const int rbase = tile * 8;
    if (rbase >= n) return;
    const int nr = min(8, n - rbase);

    __shared__ float s_x[8 * XDIM];   // 16 KB
    __shared__ int s_rows[8];
    const int t = threadIdx.x;
    if (t < nr) s_rows[t] = rows[c * CAP + rbase + t];
    __syncthreads();

    // gather x rows into LDS (128 float4 per row)
    for (int j = t; j < nr * 128; j += 256) {
        int i = j >> 7, e = j & 127;
        ((float4*)(s_x + i * XDIM))[e] = ((const float4*)(x + (size_t)s_rows[i] * XDIM))[e];
    }
    __syncthreads();

    const int hq = t & 63;
    const int rg = t >> 6;
    const int col = colbase + 2 * hq;
    const int r0 = rg * 2;

    float a00 = 0.f, a01 = 0.f, a10 = 0.f, a11 = 0.f;
    {
        const float2* wp = (const float2*)(l2_W + (size_t)c * XDIM * OUTD) + (col >> 1);
        const float* v0p = s_x + r0 * XDIM;
        const float* v1p = s_x + (r0 + 1) * XDIM;
        #pragma unroll 8
        for (int k = 0; k < XDIM; ++k) {
            float2 w = wp[k * 128];
            float v0 = v0p[k];
            float v1 = v1p[k];
            a00 += v0 * w.x; a01 += v0 * w.y;
            a10 += v1 * w.x; a11 += v1 * w.y;
        }
    }

    const float b0 = l2_b[c * OUTD + col];
    const float b1 = l2_b[c * OUTD + col + 1];
    if (r0 < nr) {
        int g = s_rows[r0];
        ((float2*)(out + (size_t)g * OUTD))[col >> 1] = make_float2(a00 + b0, a01 + b1);
    }
    if (r0 + 1 < nr) {
        int g = s_rows[r0 + 1];
        ((float2*)(out + (size_t)g * OUTD))[col >> 1] = make_float2(a10 + b0, a11 + b1);
    }
}

extern "C" void kernel_launch(void* const* d_in, const int* in_sizes, int n_in,
                              void* d_out, int out_size, void* d_ws, size_t ws_size,
                              hipStream_t stream) {
    const float* state   = (const float*)d_in[0];
    const float* obs     = (const float*)d_in[1];
    const int*   cat_ids = (const int*)d_in[2];
    const float* obs_W   = (const float*)d_in[3];
    const float* obs_b   = (const float*)d_in[4];
    const float* state_W = (const float*)d_in[5];
    const float* state_b = (const float*)d_in[6];
    const float* l2_W    = (const float*)d_in[7];
    const float* l2_b    = (const float*)d_in[8];
    float* out = (float*)d_out;

    int* counts  = (int*)d_ws;
    int* rowsbuf = (int*)((char*)d_ws + 128);
    float* x     = (float*)((char*)d_ws + 128 * 1024);

    // zero the per-category counts (ws is poisoned before every call)
    hipMemsetAsync(d_ws, 0, 128, stream);

    bucket_kernel<<<dim3((B_N + 255) / 256), dim3(256), 0, stream>>>(cat_ids, counts, rowsbuf);

    embed_kernel<<<dim3((B_N / 8) * 2), dim3(256), 0, stream>>>(
        state, obs, cat_ids, obs_W, obs_b, state_W, state_b, x);

    l2_kernel<<<dim3(C_N, CAP / 8, 2), dim3(256), 0, stream>>>(
        x, l2_W, l2_b, counts, rowsbuf, out);
}

// Round 2
// 192.039 us; speedup vs baseline: 1.1719x; 1.1719x over previous
//
#include <hip/hip_runtime.h>

// Problem constants (fixed by the reference)
constexpr int B_N   = 2048;
constexpr int C_N   = 32;
constexpr int SD    = 64;    // STATE_DIM
constexpr int EMB   = 256;
constexpr int OUTD  = 256;
constexpr int OBSD  = 512;
constexpr int XDIM  = 512;   // concat dim
constexpr int CAP   = 512;   // per-category row capacity (mean 64, 512 is >50 sigma)

// ws layout:
//   [0, 128)            int counts[32]
//   [128, 128+32*CAP*4) int rows[32][CAP]
//   [128K, 128K+4MB)    float x[B][512]   (cols 0..255 = state_emb, 256..511 = obs_emb)

__global__ void bucket_kernel(const int* __restrict__ cat_ids,
                              int* __restrict__ counts,
                              int* __restrict__ rows) {
    int t = blockIdx.x * blockDim.x + threadIdx.x;
    if (t < B_N) {
        int c = cat_ids[t];
        int slot = atomicAdd(&counts[c], 1);
        if (slot < CAP) rows[c * CAP + slot] = t;
    }
}

// 8 batch rows x 128 output cols per block; 256 threads.
// grid.x = (B/8) * 2 ; bid>>1 = row tile, bid&1 = col half.
__global__ __launch_bounds__(256, 4) void embed_kernel(
    const float* __restrict__ state, const float* __restrict__ obs,
    const int* __restrict__ cat_ids,
    const float* __restrict__ obs_W, const float* __restrict__ obs_b,
    const float* __restrict__ state_W, const float* __restrict__ state_b,
    float* __restrict__ x) {
    __shared__ float s_obs[8 * OBSD];   // 16 KB
    __shared__ float s_state[8 * SD];   // 2 KB

    const int bid = blockIdx.x;
    const int bm0 = (bid >> 1) * 8;
    const int colbase = (bid & 1) * 128;
    const int t = threadIdx.x;

    // Stage obs tile: 8*512 = 4096 contiguous floats
    {
        const float4* src = (const float4*)(obs + (size_t)bm0 * OBSD);
        float4* dst = (float4*)s_obs;
        #pragma unroll
        for (int j = 0; j < 4; ++j) dst[t + 256 * j] = src[t + 256 * j];
    }
    // Stage state tile: 8*64 = 512 contiguous floats
    if (t < 128) {
        ((float4*)s_state)[t] = ((const float4*)(state + (size_t)bm0 * SD))[t];
    }
    __syncthreads();

    const int hq = t & 63;          // lane -> 2 columns
    const int rg = t >> 6;          // wave -> 2 rows (wave-uniform)
    const int col = colbase + 2 * hq;
    const int r0 = rg * 2;

    // ---- obs_emb: K=512, shared weights, 16-deep register prefetch ring ----
    float o00 = 0.f, o01 = 0.f, o10 = 0.f, o11 = 0.f;
    {
        constexpr int PF = 16;
        const float2* wp = (const float2*)obs_W + (col >> 1);
        const float* a0p = s_obs + r0 * OBSD;
        const float* a1p = s_obs + (r0 + 1) * OBSD;
        float2 wbuf[PF];
        #pragma unroll
        for (int j = 0; j < PF; ++j) wbuf[j] = wp[j * 128];
        for (int k = 0; k < OBSD - PF; k += PF) {
            #pragma unroll
            for (int j = 0; j < PF; ++j) {
                float2 w = wbuf[j];
                wbuf[j] = wp[(k + PF + j) * 128];
                float a0 = a0p[k + j];
                float a1 = a1p[k + j];
                o00 += a0 * w.x; o01 += a0 * w.y;
                o10 += a1 * w.x; o11 += a1 * w.y;
            }
        }
        #pragma unroll
        for (int j = 0; j < PF; ++j) {
            float2 w = wbuf[j];
            float a0 = a0p[OBSD - PF + j];
            float a1 = a1p[OBSD - PF + j];
            o00 += a0 * w.x; o01 += a0 * w.y;
            o10 += a1 * w.x; o11 += a1 * w.y;
        }
    }

    // ---- state_emb: K=64, per-row category weights, 8-deep prefetch x2 streams ----
    const int g0 = bm0 + r0;
    const int g1 = bm0 + r0 + 1;
    const int c0 = cat_ids[g0];
    const int c1 = cat_ids[g1];
    float s00 = 0.f, s01 = 0.f, s10 = 0.f, s11 = 0.f;
    {
        constexpr int PF = 8;
        const float2* w0p = (const float2*)(state_W + (size_t)c0 * SD * EMB) + (col >> 1);
        const float2* w1p = (const float2*)(state_W + (size_t)c1 * SD * EMB) + (col >> 1);
        const float* a0p = s_state + r0 * SD;
        const float* a1p = s_state + (r0 + 1) * SD;
        float2 w0buf[PF], w1buf[PF];
        #pragma unroll
        for (int j = 0; j < PF; ++j) { w0buf[j] = w0p[j * 128]; w1buf[j] = w1p[j * 128]; }
        for (int k = 0; k < SD - PF; k += PF) {
            #pragma unroll
            for (int j = 0; j < PF; ++j) {
                float2 w0 = w0buf[j];
                float2 w1 = w1buf[j];
                w0buf[j] = w0p[(k + PF + j) * 128];
                w1buf[j] = w1p[(k + PF + j) * 128];
                float a0 = a0p[k + j];
                float a1 = a1p[k + j];
                s00 += a0 * w0.x; s01 += a0 * w0.y;
                s10 += a1 * w1.x; s11 += a1 * w1.y;
            }
        }
        #pragma unroll
        for (int j = 0; j < PF; ++j) {
            float2 w0 = w0buf[j];
            float2 w1 = w1buf[j];
            float a0 = a0p[SD - PF + j];
            float a1 = a1p[SD - PF + j];
            s00 += a0 * w0.x; s01 += a0 * w0.y;
            s10 += a1 * w1.x; s11 += a1 * w1.y;
        }
    }

    // biases + relu
    s00 = fmaxf(s00 + state_b[c0 * EMB + col], 0.f);
    s01 = fmaxf(s01 + state_b[c0 * EMB + col + 1], 0.f);
    s10 = fmaxf(s10 + state_b[c1 * EMB + col], 0.f);
    s11 = fmaxf(s11 + state_b[c1 * EMB + col + 1], 0.f);
    float ob0 = obs_b[col], ob1 = obs_b[col + 1];
    o00 += ob0; o01 += ob1; o10 += ob0; o11 += ob1;

    // write x: state part at cols [0,256), obs part at [256,512)
    float2* x0 = (float2*)(x + (size_t)g0 * XDIM);
    float2* x1 = (float2*)(x + (size_t)g1 * XDIM);
    x0[col >> 1] = make_float2(s00, s01);
    x0[(EMB + col) >> 1] = make_float2(o00, o01);
    x1[col >> 1] = make_float2(s10, s11);
    x1[(EMB + col) >> 1] = make_float2(o10, o11);
}

// grid: (32 cats, CAP/8 tiles, 2 col halves); 256 threads.
__global__ __launch_bounds__(256, 4) void l2_kernel(
    const float* __restrict__ x, const float* __restrict__ l2_W,
    const float* __restrict__ l2_b, const int* __restrict__ counts,
    const int* __restrict__ rows, float* __restrict__ out) {
    const int c = blockIdx.x;
    const int tile = blockIdx.y;
    const int colbase = blockIdx.z * 128;
    const int n = counts[c];
    const int rbase = tile * 8;
    if (rbase >= n) return;
    const int nr = min(8, n - rbase);

    __shared__ float s_x[8 * XDIM];   // 16 KB
    __shared__ int s_rows[8];
    const int t = threadIdx.x;
    if (t < nr) s_rows[t] = rows[c * CAP + rbase + t];
    __syncthreads();

    // gather x rows into LDS (128 float4 per row)
    for (int j = t; j < nr * 128; j += 256) {
        int i = j >> 7, e = j & 127;
        ((float4*)(s_x + i * XDIM))[e] = ((const float4*)(x + (size_t)s_rows[i] * XDIM))[e];
    }
    __syncthreads();

    const int hq = t & 63;
    const int rg = t >> 6;
    const int col = colbase + 2 * hq;
    const int r0 = rg * 2;

    float a00 = 0.f, a01 = 0.f, a10 = 0.f, a11 = 0.f;
    {
        constexpr int PF = 16;
        const float2* wp = (const float2*)(l2_W + (size_t)c * XDIM * OUTD) + (col >> 1);
        const float* v0p = s_x + r0 * XDIM;
        const float* v1p = s_x + (r0 + 1) * XDIM;
        float2 wbuf[PF];
        #pragma unroll
        for (int j = 0; j < PF; ++j) wbuf[j] = wp[j * 128];
        for (int k = 0; k < XDIM - PF; k += PF) {
            #pragma unroll
            for (int j = 0; j < PF; ++j) {
                float2 w = wbuf[j];
                wbuf[j] = wp[(k + PF + j) * 128];
                float v0 = v0p[k + j];
                float v1 = v1p[k + j];
                a00 += v0 * w.x; a01 += v0 * w.y;
                a10 += v1 * w.x; a11 += v1 * w.y;
            }
        }
        #pragma unroll
        for (int j = 0; j < PF; ++j) {
            float2 w = wbuf[j];
            float v0 = v0p[XDIM - PF + j];
            float v1 = v1p[XDIM - PF + j];
            a00 += v0 * w.x; a01 += v0 * w.y;
            a10 += v1 * w.x; a11 += v1 * w.y;
        }
    }

    const float b0 = l2_b[c * OUTD + col];
    const float b1 = l2_b[c * OUTD + col + 1];
    if (r0 < nr) {
        int g = s_rows[r0];
        ((float2*)(out + (size_t)g * OUTD))[col >> 1] = make_float2(a00 + b0, a01 + b1);
    }
    if (r0 + 1 < nr) {
        int g = s_rows[r0 + 1];
        ((float2*)(out + (size_t)g * OUTD))[col >> 1] = make_float2(a10 + b0, a11 + b1);
    }
}

extern "C" void kernel_launch(void* const* d_in, const int* in_sizes, int n_in,
                              void* d_out, int out_size, void* d_ws, size_t ws_size,
                              hipStream_t stream) {
    const float* state   = (const float*)d_in[0];
    const float* obs     = (const float*)d_in[1];
    const int*   cat_ids = (const int*)d_in[2];
    const float* obs_W   = (const float*)d_in[3];
    const float* obs_b   = (const float*)d_in[4];
    const float* state_W = (const float*)d_in[5];
    const float* state_b = (const float*)d_in[6];
    const float* l2_W    = (const float*)d_in[7];
    const float* l2_b    = (const float*)d_in[8];
    float* out = (float*)d_out;

    int* counts  = (int*)d_ws;
    int* rowsbuf = (int*)((char*)d_ws + 128);
    float* x     = (float*)((char*)d_ws + 128 * 1024);

    // zero the per-category counts (ws is poisoned before every call)
    hipMemsetAsync(d_ws, 0, 128, stream);

    bucket_kernel<<<dim3((B_N + 255) / 256), dim3(256), 0, stream>>>(cat_ids, counts, rowsbuf);

    embed_kernel<<<dim3((B_N / 8) * 2), dim3(256), 0, stream>>>(
        state, obs, cat_ids, obs_W, obs_b, state_W, state_b, x);

    l2_kernel<<<dim3(C_N, CAP / 8, 2), dim3(256), 0, stream>>>(
        x, l2_W, l2_b, counts, rowsbuf, out);
}

// Round 3
// 129.361 us; speedup vs baseline: 1.7396x; 1.4845x over previous
//
#include <hip/hip_runtime.h>

// Problem constants (fixed by the reference)
constexpr int B_N   = 2048;
constexpr int C_N   = 32;
constexpr int SD    = 64;    // STATE_DIM
constexpr int EMB   = 256;
constexpr int OUTD  = 256;
constexpr int OBSD  = 512;
constexpr int XDIM  = 512;   // concat dim
constexpr int CAP   = 256;   // per-category row capacity (mean 64, max ~100 at 5 sigma)
constexpr int TILES = CAP / 16;

typedef __attribute__((ext_vector_type(8))) short bf16x8;
typedef __attribute__((ext_vector_type(4))) float f32x4;

// ws layout (bytes):
//   0        : int counts[32]
//   4096     : int rows[32][CAP]            (32 KB)
//   65536    : packed obs_W   bf16          (256 KB)
//   327680   : packed state_W bf16          (1 MB)
//   1376256  : packed l2_W    bf16          (8 MB)   [only if ws_size allows]
constexpr size_t OFF_ROWS  = 4096;
constexpr size_t OFF_POBS  = 65536;
constexpr size_t OFF_PSTAT = 327680;
constexpr size_t OFF_PL2   = 1376256;
constexpr size_t NEED_L2   = OFF_PL2 + (size_t)C_N * XDIM * OUTD * 2;  // ~9.3 MB

__device__ __forceinline__ unsigned short bf_cvt(float f) {
    union { float f; unsigned u; } x; x.f = f;
    unsigned r = x.u + 0x7FFF + ((x.u >> 16) & 1);   // RNE
    return (unsigned short)(r >> 16);
}

__global__ void bucket_kernel(const int* __restrict__ cat_ids,
                              int* __restrict__ counts,
                              int* __restrict__ rows) {
    int t = blockIdx.x * blockDim.x + threadIdx.x;
    if (t < B_N) {
        int c = cat_ids[t];
        int slot = atomicAdd(&counts[c], 1);
        if (slot < CAP) rows[c * CAP + slot] = t;
    }
}

// Pack W (K x 256 fp32, row-major) into MFMA-B-fragment order bf16:
//   out[((chunk*16 + strip)*64 + lane)*8 + j] = W[chunk*32 + (lane>>4)*8 + j][strip*16 + (lane&15)]
// Task space: obs_W 16384 | state_W 65536 | l2_W 524288 (if do_l2)
__global__ __launch_bounds__(256) void pack_kernel(
    const float* __restrict__ obs_W, const float* __restrict__ state_W,
    const float* __restrict__ l2_W,
    unsigned short* __restrict__ p_obs, unsigned short* __restrict__ p_state,
    unsigned short* __restrict__ p_l2, int do_l2) {
    int T = blockIdx.x * 256 + threadIdx.x;
    const float* s;
    unsigned short* d;
    if (T < 16384) {                       // obs_W: K=512 -> 16 chunks
        int cs = T >> 6, lane = T & 63;
        int chunk = cs >> 4, strip = cs & 15;
        int row0 = chunk * 32 + (lane >> 4) * 8, col = strip * 16 + (lane & 15);
        s = obs_W + (size_t)row0 * 256 + col;
        d = p_obs + (size_t)T * 8;
    } else if (T < 81920) {                // state_W: 32 mats, K=64 -> 2 chunks
        int T2 = T - 16384;
        int mat = T2 >> 11, rem = T2 & 2047;
        int chunk = rem >> 10, strip = (rem >> 6) & 15, lane = rem & 63;
        int row0 = chunk * 32 + (lane >> 4) * 8, col = strip * 16 + (lane & 15);
        s = state_W + (size_t)mat * SD * 256 + (size_t)row0 * 256 + col;
        d = p_state + (size_t)T2 * 8;
    } else if (do_l2 && T < 606208) {      // l2_W: 32 mats, K=512 -> 16 chunks
        int T3 = T - 81920;
        int mat = T3 >> 14, rem = T3 & 16383;
        int chunk = rem >> 10, strip = (rem >> 6) & 15, lane = rem & 63;
        int row0 = chunk * 32 + (lane >> 4) * 8, col = strip * 16 + (lane & 15);
        s = l2_W + (size_t)mat * XDIM * 256 + (size_t)row0 * 256 + col;
        d = p_l2 + (size_t)T3 * 8;
    } else {
        return;
    }
    unsigned short v[8];
    #pragma unroll
    for (int j = 0; j < 8; ++j) v[j] = bf_cvt(s[j * 256]);
    *(bf16x8*)d = *(bf16x8*)v;   // 16B aligned store
}

// One block per (cat, 16-row tile). 4 waves; wave w owns col strips 4w..4w+3.
__global__ __launch_bounds__(256) void fused_kernel(
    const float* __restrict__ state, const float* __restrict__ obs,
    const float* __restrict__ obs_b, const float* __restrict__ state_b,
    const float* __restrict__ l2_W, const float* __restrict__ l2_b,
    const int* __restrict__ counts, const int* __restrict__ rows,
    const unsigned short* __restrict__ p_obs,
    const unsigned short* __restrict__ p_state,
    const unsigned short* __restrict__ p_l2, int has_pl2,
    float* __restrict__ out) {
    const int c = blockIdx.x;
    const int tile = blockIdx.y;
    const int n = counts[c];
    const int rbase = tile * 16;
    if (rbase >= n) return;
    const int nr = min(16, n - rbase);

    __shared__ __align__(16) unsigned short sAs[16 * 72];    // state rows (pad 64->72)
    __shared__ __align__(16) unsigned short sAo[16 * 520];   // obs rows (pad 512->520)
    __shared__ __align__(16) unsigned short sX[16 * 520];    // x rows (pad 512->520)
    __shared__ int sRows[16];

    const int t = threadIdx.x;
    if (t < 16) sRows[t] = (t < nr) ? rows[c * CAP + rbase + t] : 0;
    __syncthreads();

    // Gather + fp32->bf16: state 16x64, obs 16x512 (rows >= nr zeroed)
    for (int e = t; e < 16 * SD; e += 256) {
        int i = e >> 6, j = e & 63;
        float v = (i < nr) ? state[(size_t)sRows[i] * SD + j] : 0.f;
        sAs[i * 72 + j] = bf_cvt(v);
    }
    for (int e = t; e < 16 * OBSD; e += 256) {
        int i = e >> 9, j = e & 511;
        float v = (i < nr) ? obs[(size_t)sRows[i] * OBSD + j] : 0.f;
        sAo[i * 520 + j] = bf_cvt(v);
    }
    __syncthreads();

    const int w = t >> 6, l = t & 63;
    const int ml = l & 15, quad = l >> 4;

    // ---- Phase 1: state_emb = relu(A_s x state_W[c] + b)  (K=64: 2 chunks) ----
    {
        f32x4 acc[4];
        #pragma unroll
        for (int si = 0; si < 4; ++si) acc[si] = (f32x4){0.f, 0.f, 0.f, 0.f};
        const bf16x8* pb = (const bf16x8*)(p_state + (size_t)c * SD * 256);
        #pragma unroll
        for (int kk = 0; kk < 2; ++kk) {
            bf16x8 a = *(const bf16x8*)&sAs[ml * 72 + kk * 32 + quad * 8];
            #pragma unroll
            for (int si = 0; si < 4; ++si) {
                int strip = w * 4 + si;
                bf16x8 b = pb[(kk * 16 + strip) * 64 + l];
                acc[si] = __builtin_amdgcn_mfma_f32_16x16x32_bf16(a, b, acc[si], 0, 0, 0);
            }
        }
        #pragma unroll
        for (int si = 0; si < 4; ++si) {
            int colb = (w * 4 + si) * 16 + ml;
            float bias = state_b[c * 256 + colb];
            #pragma unroll
            for (int r = 0; r < 4; ++r) {
                int row = quad * 4 + r;
                float v = fmaxf(acc[si][r] + bias, 0.f);
                sX[row * 520 + colb] = bf_cvt(v);
            }
        }
    }

    // ---- Phase 2: obs_emb = A_o x obs_W + b  (K=512: 16 chunks) ----
    {
        f32x4 acc[4];
        #pragma unroll
        for (int si = 0; si < 4; ++si) acc[si] = (f32x4){0.f, 0.f, 0.f, 0.f};
        const bf16x8* pb = (const bf16x8*)p_obs;
        #pragma unroll
        for (int kk = 0; kk < 16; ++kk) {
            bf16x8 a = *(const bf16x8*)&sAo[ml * 520 + kk * 32 + quad * 8];
            #pragma unroll
            for (int si = 0; si < 4; ++si) {
                int strip = w * 4 + si;
                bf16x8 b = pb[(kk * 16 + strip) * 64 + l];
                acc[si] = __builtin_amdgcn_mfma_f32_16x16x32_bf16(a, b, acc[si], 0, 0, 0);
            }
        }
        #pragma unroll
        for (int si = 0; si < 4; ++si) {
            int colb = (w * 4 + si) * 16 + ml;
            float bias = obs_b[colb];
            #pragma unroll
            for (int r = 0; r < 4; ++r) {
                int row = quad * 4 + r;
                sX[row * 520 + 256 + colb] = bf_cvt(acc[si][r] + bias);
            }
        }
    }
    __syncthreads();

    // ---- Phase 3: out = x @ l2_W[c] + b  (K=512: 16 chunks) ----
    {
        f32x4 acc[4];
        #pragma unroll
        for (int si = 0; si < 4; ++si) acc[si] = (f32x4){0.f, 0.f, 0.f, 0.f};
        if (has_pl2) {
            const bf16x8* pb = (const bf16x8*)p_l2 + (size_t)c * 16384;
            #pragma unroll
            for (int kk = 0; kk < 16; ++kk) {
                bf16x8 a = *(const bf16x8*)&sX[ml * 520 + kk * 32 + quad * 8];
                #pragma unroll
                for (int si = 0; si < 4; ++si) {
                    int strip = w * 4 + si;
                    bf16x8 b = pb[(kk * 16 + strip) * 64 + l];
                    acc[si] = __builtin_amdgcn_mfma_f32_16x16x32_bf16(a, b, acc[si], 0, 0, 0);
                }
            }
        } else {
            // fallback: gather unpacked fp32 l2_W and convert on the fly
            for (int kk = 0; kk < 16; ++kk) {
                bf16x8 a = *(const bf16x8*)&sX[ml * 520 + kk * 32 + quad * 8];
                #pragma unroll
                for (int si = 0; si < 4; ++si) {
                    int strip = w * 4 + si;
                    const float* wsrc = l2_W + ((size_t)c * XDIM + kk * 32 + quad * 8) * 256
                                        + strip * 16 + ml;
                    bf16x8 b;
                    #pragma unroll
                    for (int j = 0; j < 8; ++j) b[j] = (short)bf_cvt(wsrc[j * 256]);
                    acc[si] = __builtin_amdgcn_mfma_f32_16x16x32_bf16(a, b, acc[si], 0, 0, 0);
                }
            }
        }
        #pragma unroll
        for (int si = 0; si < 4; ++si) {
            int colb = (w * 4 + si) * 16 + ml;
            float bias = l2_b[c * 256 + colb];
            #pragma unroll
            for (int r = 0; r < 4; ++r) {
                int row = quad * 4 + r;
                if (row < nr)
                    out[(size_t)sRows[row] * 256 + colb] = acc[si][r] + bias;
            }
        }
    }
}

extern "C" void kernel_launch(void* const* d_in, const int* in_sizes, int n_in,
                              void* d_out, int out_size, void* d_ws, size_t ws_size,
                              hipStream_t stream) {
    const float* state   = (const float*)d_in[0];
    const float* obs     = (const float*)d_in[1];
    const int*   cat_ids = (const int*)d_in[2];
    const float* obs_W   = (const float*)d_in[3];
    const float* obs_b   = (const float*)d_in[4];
    const float* state_W = (const float*)d_in[5];
    const float* state_b = (const float*)d_in[6];
    const float* l2_W    = (const float*)d_in[7];
    const float* l2_b    = (const float*)d_in[8];
    float* out = (float*)d_out;

    char* ws = (char*)d_ws;
    int* counts  = (int*)ws;
    int* rowsbuf = (int*)(ws + OFF_ROWS);
    unsigned short* p_obs  = (unsigned short*)(ws + OFF_POBS);
    unsigned short* p_stat = (unsigned short*)(ws + OFF_PSTAT);
    unsigned short* p_l2   = (unsigned short*)(ws + OFF_PL2);
    const int do_l2 = (ws_size >= NEED_L2) ? 1 : 0;

    hipMemsetAsync(counts, 0, 128, stream);

    bucket_kernel<<<dim3((B_N + 255) / 256), dim3(256), 0, stream>>>(cat_ids, counts, rowsbuf);

    int pack_tasks = do_l2 ? 606208 : 81920;
    pack_kernel<<<dim3(pack_tasks / 256), dim3(256), 0, stream>>>(
        obs_W, state_W, l2_W, p_obs, p_stat, p_l2, do_l2);

    fused_kernel<<<dim3(C_N, TILES), dim3(256), 0, stream>>>(
        state, obs, obs_b, state_b, l2_W, l2_b, counts, rowsbuf,
        p_obs, p_stat, p_l2, do_l2, out);
}

// Round 4
// 120.217 us; speedup vs baseline: 1.8720x; 1.0761x over previous
//
#include <hip/hip_runtime.h>

// Problem constants (fixed by the reference)
constexpr int B_N   = 2048;
constexpr int C_N   = 32;
constexpr int SD    = 64;    // STATE_DIM
constexpr int EMB   = 256;
constexpr int OUTD  = 256;
constexpr int OBSD  = 512;
constexpr int XDIM  = 512;   // concat dim
constexpr int CAP   = 256;   // per-category row capacity (mean 64, ~96 at 4 sigma)

typedef __attribute__((ext_vector_type(8))) short bf16x8;
typedef __attribute__((ext_vector_type(4))) short bf16x4;
typedef __attribute__((ext_vector_type(4))) float f32x4;

// ws layout (bytes):
//   0        : int counts[32]
//   4096     : int rows[32][CAP]            (32 KB)
//   65536    : packed obs_W   bf16          (256 KB)
//   327680   : packed state_W bf16          (1 MB)
//   1376256  : packed l2_W    bf16          (8 MB)
constexpr size_t OFF_ROWS  = 4096;
constexpr size_t OFF_POBS  = 65536;
constexpr size_t OFF_PSTAT = 327680;
constexpr size_t OFF_PL2   = 1376256;
constexpr size_t NEED_L2   = OFF_PL2 + (size_t)C_N * XDIM * OUTD * 2;

__device__ __forceinline__ unsigned short bf_cvt(float f) {
    union { float f; unsigned u; } x; x.f = f;
    unsigned r = x.u + 0x7FFF + ((x.u >> 16) & 1);   // RNE
    return (unsigned short)(r >> 16);
}

// Fragment layout (B-operand of mfma_f32_16x16x32_bf16), per K-chunk of 32:
//   p[((chunk*16 + strip)*64 + lane)*8 + j] = W[chunk*32 + (lane>>4)*8 + j][strip*16 + (lane&15)]
//
// prep_kernel: blocks 0..31 = bucket per category (no global atomics, no memset
// needed); blocks 32..47 obs_W chunks; 48..111 state_W (32 mats x 2 chunks);
// 112..623 l2_W (32 mats x 16 chunks). Pack path: coalesced float4 stage ->
// LDS bf16 -> coalesced 16B fragment stores.
__global__ __launch_bounds__(256) void prep_kernel(
    const int* __restrict__ cat_ids,
    const float* __restrict__ obs_W, const float* __restrict__ state_W,
    const float* __restrict__ l2_W,
    int* __restrict__ counts, int* __restrict__ rows,
    unsigned short* __restrict__ p_obs, unsigned short* __restrict__ p_state,
    unsigned short* __restrict__ p_l2, int do_l2) {
    const int bid = blockIdx.x;
    const int t = threadIdx.x;

    if (bid < C_N) {
        // ---- bucket for category c = bid ----
        __shared__ int cnt;
        __shared__ int list[CAP];
        if (t == 0) cnt = 0;
        __syncthreads();
        const int c = bid;
        for (int r = t; r < B_N; r += 256) {
            if (cat_ids[r] == c) {
                int s = atomicAdd(&cnt, 1);
                if (s < CAP) list[s] = r;
            }
        }
        __syncthreads();
        int n = min(cnt, CAP);
        for (int s = t; s < n; s += 256) rows[c * CAP + s] = list[s];
        if (t == 0) counts[c] = n;
        return;
    }

    // ---- pack one 32-row K-chunk of one weight matrix ----
    const float* src;
    unsigned short* dst;
    {
        int pb = bid - C_N;
        if (pb < 16) {                       // obs_W, chunk = pb
            src = obs_W + (size_t)pb * 32 * 256;
            dst = p_obs + (size_t)pb * 8192;
        } else if (pb < 80) {                // state_W: i = mat*2 + chunk
            int i = pb - 16;
            int mat = i >> 1, ch = i & 1;
            src = state_W + ((size_t)mat * SD + ch * 32) * 256;
            dst = p_state + (size_t)i * 8192;
        } else {                             // l2_W: i = mat*16 + chunk
            if (!do_l2) return;
            int i = pb - 80;
            int mat = i >> 4, ch = i & 15;
            src = l2_W + ((size_t)mat * XDIM + ch * 32) * 256;
            dst = p_l2 + (size_t)i * 8192;
        }
    }

    __shared__ __align__(16) unsigned short sW[32 * 264];   // 32 rows, pad 256->264
    #pragma unroll
    for (int i2 = 0; i2 < 8; ++i2) {
        int f = t + 256 * i2;                // float4 index in contiguous 32x256 block
        int row = f >> 6, c4 = f & 63;
        float4 v = ((const float4*)src)[f];
        unsigned short* d = &sW[row * 264 + c4 * 4];
        d[0] = bf_cvt(v.x); d[1] = bf_cvt(v.y); d[2] = bf_cvt(v.z); d[3] = bf_cvt(v.w);
    }
    __syncthreads();
    #pragma unroll
    for (int s4 = 0; s4 < 4; ++s4) {
        int slot = s4 * 256 + t;             // (strip,lane) slot, 1024 total
        int strip = slot >> 6, lane = slot & 63;
        int r0 = (lane >> 4) * 8, col = strip * 16 + (lane & 15);
        unsigned short v[8];
        #pragma unroll
        for (int j = 0; j < 8; ++j) v[j] = sW[(r0 + j) * 264 + col];
        *(bf16x8*)(dst + (size_t)slot * 8) = *(bf16x8*)v;
    }
}

// One block per (cat, 8-row tile). 4 waves; wave w owns col strips 4w..4w+3.
// MFMA tiles are 16 rows; rows nr..15 are zero-padded (free — latency-bound).
__global__ __launch_bounds__(256) void fused_kernel(
    const float* __restrict__ state, const float* __restrict__ obs,
    const float* __restrict__ obs_b, const float* __restrict__ state_b,
    const float* __restrict__ l2_W, const float* __restrict__ l2_b,
    const int* __restrict__ counts, const int* __restrict__ rows,
    const unsigned short* __restrict__ p_obs,
    const unsigned short* __restrict__ p_state,
    const unsigned short* __restrict__ p_l2, int has_pl2,
    float* __restrict__ out) {
    const int c = blockIdx.x;
    const int tile = blockIdx.y;
    const int n = counts[c];
    const int rbase = tile * 8;
    if (rbase >= n) return;
    const int nr = min(8, n - rbase);

    __shared__ __align__(16) unsigned short sAs[16 * 72];    // state rows (pad 64->72)
    __shared__ __align__(16) unsigned short sAo[16 * 520];   // obs rows (pad 512->520)
    __shared__ __align__(16) unsigned short sX[16 * 520];    // x rows (pad 512->520)
    __shared__ int sRows[16];

    const int t = threadIdx.x;
    if (t < 16) sRows[t] = (t < nr) ? rows[c * CAP + rbase + t] : 0;
    __syncthreads();

    // Gather + fp32->bf16 (coalesced float4; rows >= nr zeroed)
    {   // state: 16 rows x 64 cols = 256 float4 slots, one per thread
        int i = t >> 4, c4 = t & 15;
        unsigned short vv[4] = {0, 0, 0, 0};
        if (i < nr) {
            float4 v = ((const float4*)(state + (size_t)sRows[i] * SD))[c4];
            vv[0] = bf_cvt(v.x); vv[1] = bf_cvt(v.y); vv[2] = bf_cvt(v.z); vv[3] = bf_cvt(v.w);
        }
        *(bf16x4*)&sAs[i * 72 + c4 * 4] = *(bf16x4*)vv;
    }
    #pragma unroll
    for (int i2 = 0; i2 < 8; ++i2) {         // obs: 16 rows x 512 = 2048 float4 slots
        int f = t + 256 * i2;
        int i = f >> 7, c4 = f & 127;
        unsigned short vv[4] = {0, 0, 0, 0};
        if (i < nr) {
            float4 v = ((const float4*)(obs + (size_t)sRows[i] * OBSD))[c4];
            vv[0] = bf_cvt(v.x); vv[1] = bf_cvt(v.y); vv[2] = bf_cvt(v.z); vv[3] = bf_cvt(v.w);
        }
        *(bf16x4*)&sAo[i * 520 + c4 * 4] = *(bf16x4*)vv;
    }
    __syncthreads();

    const int w = t >> 6, l = t & 63;
    const int ml = l & 15, quad = l >> 4;

    // ---- Phase 1: state_emb = relu(A_s x state_W[c] + b)  (K=64: 2 chunks) ----
    {
        f32x4 acc[4];
        #pragma unroll
        for (int si = 0; si < 4; ++si) acc[si] = (f32x4){0.f, 0.f, 0.f, 0.f};
        const bf16x8* pb = (const bf16x8*)(p_state + (size_t)c * SD * 256);
        #pragma unroll
        for (int kk = 0; kk < 2; ++kk) {
            bf16x8 a = *(const bf16x8*)&sAs[ml * 72 + kk * 32 + quad * 8];
            #pragma unroll
            for (int si = 0; si < 4; ++si) {
                int strip = w * 4 + si;
                bf16x8 b = pb[(kk * 16 + strip) * 64 + l];
                acc[si] = __builtin_amdgcn_mfma_f32_16x16x32_bf16(a, b, acc[si], 0, 0, 0);
            }
        }
        #pragma unroll
        for (int si = 0; si < 4; ++si) {
            int colb = (w * 4 + si) * 16 + ml;
            float bias = state_b[c * 256 + colb];
            #pragma unroll
            for (int r = 0; r < 4; ++r) {
                int row = quad * 4 + r;
                sX[row * 520 + colb] = bf_cvt(fmaxf(acc[si][r] + bias, 0.f));
            }
        }
    }

    // ---- Phase 2: obs_emb = A_o x obs_W + b  (K=512: 16 chunks) ----
    {
        f32x4 acc[4];
        #pragma unroll
        for (int si = 0; si < 4; ++si) acc[si] = (f32x4){0.f, 0.f, 0.f, 0.f};
        const bf16x8* pb = (const bf16x8*)p_obs;
        #pragma unroll
        for (int kk = 0; kk < 16; ++kk) {
            bf16x8 a = *(const bf16x8*)&sAo[ml * 520 + kk * 32 + quad * 8];
            #pragma unroll
            for (int si = 0; si < 4; ++si) {
                int strip = w * 4 + si;
                bf16x8 b = pb[(kk * 16 + strip) * 64 + l];
                acc[si] = __builtin_amdgcn_mfma_f32_16x16x32_bf16(a, b, acc[si], 0, 0, 0);
            }
        }
        #pragma unroll
        for (int si = 0; si < 4; ++si) {
            int colb = (w * 4 + si) * 16 + ml;
            float bias = obs_b[colb];
            #pragma unroll
            for (int r = 0; r < 4; ++r) {
                int row = quad * 4 + r;
                sX[row * 520 + 256 + colb] = bf_cvt(acc[si][r] + bias);
            }
        }
    }
    __syncthreads();

    // ---- Phase 3: out = x @ l2_W[c] + b  (K=512: 16 chunks) ----
    {
        f32x4 acc[4];
        #pragma unroll
        for (int si = 0; si < 4; ++si) acc[si] = (f32x4){0.f, 0.f, 0.f, 0.f};
        if (has_pl2) {
            const bf16x8* pb = (const bf16x8*)p_l2 + (size_t)c * 16384;
            #pragma unroll
            for (int kk = 0; kk < 16; ++kk) {
                bf16x8 a = *(const bf16x8*)&sX[ml * 520 + kk * 32 + quad * 8];
                #pragma unroll
                for (int si = 0; si < 4; ++si) {
                    int strip = w * 4 + si;
                    bf16x8 b = pb[(kk * 16 + strip) * 64 + l];
                    acc[si] = __builtin_amdgcn_mfma_f32_16x16x32_bf16(a, b, acc[si], 0, 0, 0);
                }
            }
        } else {
            for (int kk = 0; kk < 16; ++kk) {
                bf16x8 a = *(const bf16x8*)&sX[ml * 520 + kk * 32 + quad * 8];
                #pragma unroll
                for (int si = 0; si < 4; ++si) {
                    int strip = w * 4 + si;
                    const float* wsrc = l2_W + ((size_t)c * XDIM + kk * 32 + quad * 8) * 256
                                        + strip * 16 + ml;
                    bf16x8 b;
                    #pragma unroll
                    for (int j = 0; j < 8; ++j) b[j] = (short)bf_cvt(wsrc[j * 256]);
                    acc[si] = __builtin_amdgcn_mfma_f32_16x16x32_bf16(a, b, acc[si], 0, 0, 0);
                }
            }
        }
        #pragma unroll
        for (int si = 0; si < 4; ++si) {
            int colb = (w * 4 + si) * 16 + ml;
            float bias = l2_b[c * 256 + colb];
            #pragma unroll
            for (int r = 0; r < 4; ++r) {
                int row = quad * 4 + r;
                if (row < nr)
                    out[(size_t)sRows[row] * 256 + colb] = acc[si][r] + bias;
            }
        }
    }
}

extern "C" void kernel_launch(void* const* d_in, const int* in_sizes, int n_in,
                              void* d_out, int out_size, void* d_ws, size_t ws_size,
                              hipStream_t stream) {
    const float* state   = (const float*)d_in[0];
    const float* obs     = (const float*)d_in[1];
    const int*   cat_ids = (const int*)d_in[2];
    const float* obs_W   = (const float*)d_in[3];
    const float* obs_b   = (const float*)d_in[4];
    const float* state_W = (const float*)d_in[5];
    const float* state_b = (const float*)d_in[6];
    const float* l2_W    = (const float*)d_in[7];
    const float* l2_b    = (const float*)d_in[8];
    float* out = (float*)d_out;

    char* ws = (char*)d_ws;
    int* counts  = (int*)ws;
    int* rowsbuf = (int*)(ws + OFF_ROWS);
    unsigned short* p_obs  = (unsigned short*)(ws + OFF_POBS);
    unsigned short* p_stat = (unsigned short*)(ws + OFF_PSTAT);
    unsigned short* p_l2   = (unsigned short*)(ws + OFF_PL2);
    const int do_l2 = (ws_size >= NEED_L2) ? 1 : 0;

    int prep_blocks = C_N + 16 + 64 + (do_l2 ? 512 : 0);
    prep_kernel<<<dim3(prep_blocks), dim3(256), 0, stream>>>(
        cat_ids, obs_W, state_W, l2_W, counts, rowsbuf, p_obs, p_stat, p_l2, do_l2);

    fused_kernel<<<dim3(C_N, CAP / 8), dim3(256), 0, stream>>>(
        state, obs, obs_b, state_b, l2_W, l2_b, counts, rowsbuf,
        p_obs, p_stat, p_l2, do_l2, out);
}

// Round 5
// 99.504 us; speedup vs baseline: 2.2616x; 1.2082x over previous
//
#include <hip/hip_runtime.h>

// Problem constants (fixed by the reference)
constexpr int B_N   = 2048;
constexpr int C_N   = 32;
constexpr int SD    = 64;    // STATE_DIM
constexpr int EMB   = 256;
constexpr int OUTD  = 256;
constexpr int OBSD  = 512;
constexpr int XDIM  = 512;   // concat dim
constexpr int CAP   = 256;   // per-category row capacity (mean 64, ~96 at 4 sigma)

typedef __attribute__((ext_vector_type(8))) short bf16x8;
typedef __attribute__((ext_vector_type(4))) short bf16x4;
typedef __attribute__((ext_vector_type(4))) float f32x4;

// ws layout (bytes):
//   0        : int counts[32]
//   4096     : int rows[32][CAP]            (32 KB)
//   65536    : packed obs_W   bf16          (256 KB)
//   327680   : packed state_W bf16          (1 MB)
//   1376256  : packed l2_W    bf16          (8 MB)
constexpr size_t OFF_ROWS  = 4096;
constexpr size_t OFF_POBS  = 65536;
constexpr size_t OFF_PSTAT = 327680;
constexpr size_t OFF_PL2   = 1376256;
constexpr size_t NEED_L2   = OFF_PL2 + (size_t)C_N * XDIM * OUTD * 2;

__device__ __forceinline__ unsigned short bf_cvt(float f) {
    union { float f; unsigned u; } x; x.f = f;
    unsigned r = x.u + 0x7FFF + ((x.u >> 16) & 1);   // RNE
    return (unsigned short)(r >> 16);
}

// Fragment layout (B-operand of mfma_f32_16x16x32_bf16), per K-chunk of 32:
//   p[((chunk*16 + strip)*64 + lane)*8 + j] = W[chunk*32 + (lane>>4)*8 + j][strip*16 + (lane&15)]
__global__ __launch_bounds__(256) void prep_kernel(
    const int* __restrict__ cat_ids,
    const float* __restrict__ obs_W, const float* __restrict__ state_W,
    const float* __restrict__ l2_W,
    int* __restrict__ counts, int* __restrict__ rows,
    unsigned short* __restrict__ p_obs, unsigned short* __restrict__ p_state,
    unsigned short* __restrict__ p_l2, int do_l2) {
    const int bid = blockIdx.x;
    const int t = threadIdx.x;

    if (bid < C_N) {
        // ---- bucket for category c = bid ----
        __shared__ int cnt;
        __shared__ int list[CAP];
        if (t == 0) cnt = 0;
        __syncthreads();
        const int c = bid;
        for (int r = t; r < B_N; r += 256) {
            if (cat_ids[r] == c) {
                int s = atomicAdd(&cnt, 1);
                if (s < CAP) list[s] = r;
            }
        }
        __syncthreads();
        int n = min(cnt, CAP);
        for (int s = t; s < n; s += 256) rows[c * CAP + s] = list[s];
        if (t == 0) counts[c] = n;
        return;
    }

    // ---- pack one 32-row K-chunk of one weight matrix ----
    const float* src;
    unsigned short* dst;
    {
        int pb = bid - C_N;
        if (pb < 16) {                       // obs_W, chunk = pb
            src = obs_W + (size_t)pb * 32 * 256;
            dst = p_obs + (size_t)pb * 8192;
        } else if (pb < 80) {                // state_W: i = mat*2 + chunk
            int i = pb - 16;
            int mat = i >> 1, ch = i & 1;
            src = state_W + ((size_t)mat * SD + ch * 32) * 256;
            dst = p_state + (size_t)i * 8192;
        } else {                             // l2_W: i = mat*16 + chunk
            if (!do_l2) return;
            int i = pb - 80;
            int mat = i >> 4, ch = i & 15;
            src = l2_W + ((size_t)mat * XDIM + ch * 32) * 256;
            dst = p_l2 + (size_t)i * 8192;
        }
    }

    __shared__ __align__(16) unsigned short sW[32 * 264];   // 32 rows, pad 256->264
    #pragma unroll
    for (int i2 = 0; i2 < 8; ++i2) {
        int f = t + 256 * i2;                // float4 index in contiguous 32x256 block
        int row = f >> 6, c4 = f & 63;
        float4 v = ((const float4*)src)[f];
        unsigned short* d = &sW[row * 264 + c4 * 4];
        d[0] = bf_cvt(v.x); d[1] = bf_cvt(v.y); d[2] = bf_cvt(v.z); d[3] = bf_cvt(v.w);
    }
    __syncthreads();
    #pragma unroll
    for (int s4 = 0; s4 < 4; ++s4) {
        int slot = s4 * 256 + t;             // (strip,lane) slot, 1024 total
        int strip = slot >> 6, lane = slot & 63;
        int r0 = (lane >> 4) * 8, col = strip * 16 + (lane & 15);
        unsigned short v[8];
        #pragma unroll
        for (int j = 0; j < 8; ++j) v[j] = sW[(r0 + j) * 264 + col];
        *(bf16x8*)(dst + (size_t)slot * 8) = *(bf16x8*)v;
    }
}

// One block per (cat, 8-row tile). 512 threads = 8 waves; wave w owns col
// strips {2w, 2w+1}. MFMA tiles are 16 rows; rows nr..15 zero-padded.
__global__ __launch_bounds__(512) void fused_kernel(
    const float* __restrict__ state, const float* __restrict__ obs,
    const float* __restrict__ obs_b, const float* __restrict__ state_b,
    const float* __restrict__ l2_W, const float* __restrict__ l2_b,
    const int* __restrict__ counts, const int* __restrict__ rows,
    const unsigned short* __restrict__ p_obs,
    const unsigned short* __restrict__ p_state,
    const unsigned short* __restrict__ p_l2, int has_pl2,
    float* __restrict__ out) {
    const int c = blockIdx.x;
    const int tile = blockIdx.y;
    const int n = counts[c];
    const int rbase = tile * 8;
    if (rbase >= n) return;
    const int nr = min(8, n - rbase);

    __shared__ __align__(16) unsigned short sAs[16 * 72];    // state rows (pad 64->72)
    __shared__ __align__(16) unsigned short sAo[16 * 520];   // obs rows (pad 512->520)
    __shared__ __align__(16) unsigned short sX[16 * 520];    // x rows (pad 512->520)
    __shared__ int sRows[16];

    const int t = threadIdx.x;
    const int w = t >> 6, l = t & 63;
    const int ml = l & 15, quad = l >> 4;

    if (t < 16) sRows[t] = 0;
    __syncthreads();
    if (t < nr) sRows[t] = rows[c * CAP + rbase + t];

    // ---- Prefetch phase-1 (all 4) and phase-2 (first 4 chunks) b-fragments.
    //      These loads drain at the gather barrier -> overlap with gather.
    const bf16x8* pb1 = (const bf16x8*)(p_state + (size_t)c * SD * 256);
    const bf16x8* pb2 = (const bf16x8*)p_obs;
    bf16x8 pf1[4], pf2[8];
    #pragma unroll
    for (int kk = 0; kk < 2; ++kk)
        #pragma unroll
        for (int si = 0; si < 2; ++si)
            pf1[kk * 2 + si] = pb1[(kk * 16 + w * 2 + si) * 64 + l];
    #pragma unroll
    for (int kk = 0; kk < 4; ++kk)
        #pragma unroll
        for (int si = 0; si < 2; ++si)
            pf2[kk * 2 + si] = pb2[(kk * 16 + w * 2 + si) * 64 + l];

    __syncthreads();   // sRows visible

    // Gather + fp32->bf16 (coalesced float4; rows >= nr zeroed)
    if (t < 256) {      // state: 16 rows x 64 = 256 float4 slots
        int i = t >> 4, c4 = t & 15;
        unsigned short vv[4] = {0, 0, 0, 0};
        if (i < nr) {
            float4 v = ((const float4*)(state + (size_t)sRows[i] * SD))[c4];
            vv[0] = bf_cvt(v.x); vv[1] = bf_cvt(v.y); vv[2] = bf_cvt(v.z); vv[3] = bf_cvt(v.w);
        }
        *(bf16x4*)&sAs[i * 72 + c4 * 4] = *(bf16x4*)vv;
    }
    #pragma unroll
    for (int i2 = 0; i2 < 4; ++i2) {         // obs: 16 rows x 512 = 2048 float4 slots
        int f = t + 512 * i2;
        int i = f >> 7, c4 = f & 127;
        unsigned short vv[4] = {0, 0, 0, 0};
        if (i < nr) {
            float4 v = ((const float4*)(obs + (size_t)sRows[i] * OBSD))[c4];
            vv[0] = bf_cvt(v.x); vv[1] = bf_cvt(v.y); vv[2] = bf_cvt(v.z); vv[3] = bf_cvt(v.w);
        }
        *(bf16x4*)&sAo[i * 520 + c4 * 4] = *(bf16x4*)vv;
    }
    __syncthreads();

    // ---- Phase 1: state_emb = relu(A_s x state_W[c] + b)  (K=64: 2 chunks) ----
    {
        f32x4 acc[2];
        #pragma unroll
        for (int si = 0; si < 2; ++si) acc[si] = (f32x4){0.f, 0.f, 0.f, 0.f};
        #pragma unroll
        for (int kk = 0; kk < 2; ++kk) {
            bf16x8 a = *(const bf16x8*)&sAs[ml * 72 + kk * 32 + quad * 8];
            #pragma unroll
            for (int si = 0; si < 2; ++si)
                acc[si] = __builtin_amdgcn_mfma_f32_16x16x32_bf16(a, pf1[kk * 2 + si], acc[si], 0, 0, 0);
        }
        #pragma unroll
        for (int si = 0; si < 2; ++si) {
            int colb = (w * 2 + si) * 16 + ml;
            float bias = state_b[c * 256 + colb];
            #pragma unroll
            for (int r = 0; r < 4; ++r)
                sX[(quad * 4 + r) * 520 + colb] = bf_cvt(fmaxf(acc[si][r] + bias, 0.f));
        }
    }

    // ---- Phase 2: obs_emb = A_o x obs_W + b  (K=512: 16 chunks, ring PF=4 chunks) ----
    {
        f32x4 acc[2];
        #pragma unroll
        for (int si = 0; si < 2; ++si) acc[si] = (f32x4){0.f, 0.f, 0.f, 0.f};
        #pragma unroll
        for (int kk = 0; kk < 16; ++kk) {
            bf16x8 a = *(const bf16x8*)&sAo[ml * 520 + kk * 32 + quad * 8];
            #pragma unroll
            for (int si = 0; si < 2; ++si) {
                bf16x8 b = pf2[(kk & 3) * 2 + si];
                if (kk < 12)
                    pf2[(kk & 3) * 2 + si] = pb2[((kk + 4) * 16 + w * 2 + si) * 64 + l];
                acc[si] = __builtin_amdgcn_mfma_f32_16x16x32_bf16(a, b, acc[si], 0, 0, 0);
            }
        }
        #pragma unroll
        for (int si = 0; si < 2; ++si) {
            int colb = (w * 2 + si) * 16 + ml;
            float bias = obs_b[colb];
            #pragma unroll
            for (int r = 0; r < 4; ++r)
                sX[(quad * 4 + r) * 520 + 256 + colb] = bf_cvt(acc[si][r] + bias);
        }
    }

    // ---- Prefetch phase-3 first 4 chunks BEFORE the sX barrier ----
    const bf16x8* pb3 = (const bf16x8*)p_l2 + (size_t)c * 16384;
    bf16x8 pf3[8];
    if (has_pl2) {
        #pragma unroll
        for (int kk = 0; kk < 4; ++kk)
            #pragma unroll
            for (int si = 0; si < 2; ++si)
                pf3[kk * 2 + si] = pb3[(kk * 16 + w * 2 + si) * 64 + l];
    }
    __syncthreads();

    // ---- Phase 3: out = x @ l2_W[c] + b  (K=512: 16 chunks, ring PF=4 chunks) ----
    {
        f32x4 acc[2];
        #pragma unroll
        for (int si = 0; si < 2; ++si) acc[si] = (f32x4){0.f, 0.f, 0.f, 0.f};
        if (has_pl2) {
            #pragma unroll
            for (int kk = 0; kk < 16; ++kk) {
                bf16x8 a = *(const bf16x8*)&sX[ml * 520 + kk * 32 + quad * 8];
                #pragma unroll
                for (int si = 0; si < 2; ++si) {
                    bf16x8 b = pf3[(kk & 3) * 2 + si];
                    if (kk < 12)
                        pf3[(kk & 3) * 2 + si] = pb3[((kk + 4) * 16 + w * 2 + si) * 64 + l];
                    acc[si] = __builtin_amdgcn_mfma_f32_16x16x32_bf16(a, b, acc[si], 0, 0, 0);
                }
            }
        } else {
            for (int kk = 0; kk < 16; ++kk) {
                bf16x8 a = *(const bf16x8*)&sX[ml * 520 + kk * 32 + quad * 8];
                #pragma unroll
                for (int si = 0; si < 2; ++si) {
                    const float* wsrc = l2_W + ((size_t)c * XDIM + kk * 32 + quad * 8) * 256
                                        + (w * 2 + si) * 16 + ml;
                    bf16x8 b;
                    #pragma unroll
                    for (int j = 0; j < 8; ++j) b[j] = (short)bf_cvt(wsrc[j * 256]);
                    acc[si] = __builtin_amdgcn_mfma_f32_16x16x32_bf16(a, b, acc[si], 0, 0, 0);
                }
            }
        }
        #pragma unroll
        for (int si = 0; si < 2; ++si) {
            int colb = (w * 2 + si) * 16 + ml;
            float bias = l2_b[c * 256 + colb];
            #pragma unroll
            for (int r = 0; r < 4; ++r) {
                int row = quad * 4 + r;
                if (row < nr)
                    out[(size_t)sRows[row] * 256 + colb] = acc[si][r] + bias;
            }
        }
    }
}

extern "C" void kernel_launch(void* const* d_in, const int* in_sizes, int n_in,
                              void* d_out, int out_size, void* d_ws, size_t ws_size,
                              hipStream_t stream) {
    const float* state   = (const float*)d_in[0];
    const float* obs     = (const float*)d_in[1];
    const int*   cat_ids = (const int*)d_in[2];
    const float* obs_W   = (const float*)d_in[3];
    const float* obs_b   = (const float*)d_in[4];
    const float* state_W = (const float*)d_in[5];
    const float* state_b = (const float*)d_in[6];
    const float* l2_W    = (const float*)d_in[7];
    const float* l2_b    = (const float*)d_in[8];
    float* out = (float*)d_out;

    char* ws = (char*)d_ws;
    int* counts  = (int*)ws;
    int* rowsbuf = (int*)(ws + OFF_ROWS);
    unsigned short* p_obs  = (unsigned short*)(ws + OFF_POBS);
    unsigned short* p_stat = (unsigned short*)(ws + OFF_PSTAT);
    unsigned short* p_l2   = (unsigned short*)(ws + OFF_PL2);
    const int do_l2 = (ws_size >= NEED_L2) ? 1 : 0;

    int prep_blocks = C_N + 16 + 64 + (do_l2 ? 512 : 0);
    prep_kernel<<<dim3(prep_blocks), dim3(256), 0, stream>>>(
        cat_ids, obs_W, state_W, l2_W, counts, rowsbuf, p_obs, p_stat, p_l2, do_l2);

    fused_kernel<<<dim3(C_N, CAP / 8), dim3(512), 0, stream>>>(
        state, obs, obs_b, state_b, l2_W, l2_b, counts, rowsbuf,
        p_obs, p_stat, p_l2, do_l2, out);
}

// Round 6
// 98.161 us; speedup vs baseline: 2.2926x; 1.0137x over previous
//
#include <hip/hip_runtime.h>

// Problem constants (fixed by the reference)
constexpr int B_N   = 2048;
constexpr int C_N   = 32;
constexpr int SD    = 64;    // STATE_DIM
constexpr int EMB   = 256;
constexpr int OUTD  = 256;
constexpr int OBSD  = 512;
constexpr int XDIM  = 512;   // concat dim
constexpr int CAP   = 256;   // per-category row capacity (mean 64, ~96 at 4 sigma)

typedef __attribute__((ext_vector_type(8))) short bf16x8;
typedef __attribute__((ext_vector_type(4))) short bf16x4;
typedef __attribute__((ext_vector_type(4))) float f32x4;

// ws layout (bytes):
//   0        : int counts[32]
//   4096     : int rows[32][CAP]            (32 KB)
//   65536    : packed obs_W   bf16          (256 KB)
//   327680   : packed state_W bf16          (1 MB)
//   1376256  : packed l2_W    bf16          (8 MB)
constexpr size_t OFF_ROWS  = 4096;
constexpr size_t OFF_POBS  = 65536;
constexpr size_t OFF_PSTAT = 327680;
constexpr size_t OFF_PL2   = 1376256;
constexpr size_t NEED_L2   = OFF_PL2 + (size_t)C_N * XDIM * OUTD * 2;

__device__ __forceinline__ unsigned short bf_cvt(float f) {
    union { float f; unsigned u; } x; x.f = f;
    unsigned r = x.u + 0x7FFF + ((x.u >> 16) & 1);   // RNE
    return (unsigned short)(r >> 16);
}

// Fragment layout (B-operand of mfma_f32_16x16x32_bf16), per K-chunk of 32:
//   p[((chunk*16 + strip)*64 + lane)*8 + j] = W[chunk*32 + (lane>>4)*8 + j][strip*16 + (lane&15)]
__global__ __launch_bounds__(256) void prep_kernel(
    const int* __restrict__ cat_ids,
    const float* __restrict__ obs_W, const float* __restrict__ state_W,
    const float* __restrict__ l2_W,
    int* __restrict__ counts, int* __restrict__ rows,
    unsigned short* __restrict__ p_obs, unsigned short* __restrict__ p_state,
    unsigned short* __restrict__ p_l2, int do_l2) {
    const int bid = blockIdx.x;
    const int t = threadIdx.x;

    if (bid < C_N) {
        // ---- bucket for category c = bid ----
        __shared__ int cnt;
        __shared__ int list[CAP];
        if (t == 0) cnt = 0;
        __syncthreads();
        const int c = bid;
        for (int r = t; r < B_N; r += 256) {
            if (cat_ids[r] == c) {
                int s = atomicAdd(&cnt, 1);
                if (s < CAP) list[s] = r;
            }
        }
        __syncthreads();
        int n = min(cnt, CAP);
        for (int s = t; s < n; s += 256) rows[c * CAP + s] = list[s];
        if (t == 0) counts[c] = n;
        return;
    }

    // ---- pack one 32-row K-chunk of one weight matrix ----
    const float* src;
    unsigned short* dst;
    {
        int pb = bid - C_N;
        if (pb < 16) {                       // obs_W, chunk = pb
            src = obs_W + (size_t)pb * 32 * 256;
            dst = p_obs + (size_t)pb * 8192;
        } else if (pb < 80) {                // state_W: i = mat*2 + chunk
            int i = pb - 16;
            int mat = i >> 1, ch = i & 1;
            src = state_W + ((size_t)mat * SD + ch * 32) * 256;
            dst = p_state + (size_t)i * 8192;
        } else {                             // l2_W: i = mat*16 + chunk
            if (!do_l2) return;
            int i = pb - 80;
            int mat = i >> 4, ch = i & 15;
            src = l2_W + ((size_t)mat * XDIM + ch * 32) * 256;
            dst = p_l2 + (size_t)i * 8192;
        }
    }

    __shared__ __align__(16) unsigned short sW[32 * 264];   // 32 rows, pad 256->264
    #pragma unroll
    for (int i2 = 0; i2 < 8; ++i2) {
        int f = t + 256 * i2;                // float4 index in contiguous 32x256 block
        int row = f >> 6, c4 = f & 63;
        float4 v = ((const float4*)src)[f];
        unsigned short* d = &sW[row * 264 + c4 * 4];
        d[0] = bf_cvt(v.x); d[1] = bf_cvt(v.y); d[2] = bf_cvt(v.z); d[3] = bf_cvt(v.w);
    }
    __syncthreads();
    #pragma unroll
    for (int s4 = 0; s4 < 4; ++s4) {
        int slot = s4 * 256 + t;             // (strip,lane) slot, 1024 total
        int strip = slot >> 6, lane = slot & 63;
        int r0 = (lane >> 4) * 8, col = strip * 16 + (lane & 15);
        unsigned short v[8];
        #pragma unroll
        for (int j = 0; j < 8; ++j) v[j] = sW[(r0 + j) * 264 + col];
        *(bf16x8*)(dst + (size_t)slot * 8) = *(bf16x8*)v;
    }
}

// One block per (cat, 16-row tile). 512 threads = 8 waves; wave w owns col
// strips {2w, 2w+1}. All 16 MFMA rows are real (tile = MFMA M).
__global__ __launch_bounds__(512) void fused_kernel(
    const float* __restrict__ state, const float* __restrict__ obs,
    const float* __restrict__ obs_b, const float* __restrict__ state_b,
    const float* __restrict__ l2_W, const float* __restrict__ l2_b,
    const int* __restrict__ counts, const int* __restrict__ rows,
    const unsigned short* __restrict__ p_obs,
    const unsigned short* __restrict__ p_state,
    const unsigned short* __restrict__ p_l2, int has_pl2,
    float* __restrict__ out) {
    const int c = blockIdx.x;
    const int tile = blockIdx.y;
    const int n = counts[c];
    const int rbase = tile * 16;
    if (rbase >= n) return;
    const int nr = min(16, n - rbase);

    __shared__ __align__(16) unsigned short sAs[16 * 72];    // state rows (pad 64->72)
    __shared__ __align__(16) unsigned short sAo[16 * 520];   // obs rows (pad 512->520)
    __shared__ __align__(16) unsigned short sX[16 * 520];    // x rows (pad 512->520)
    __shared__ int sRows[16];

    const int t = threadIdx.x;
    const int w = t >> 6, l = t & 63;
    const int ml = l & 15, quad = l >> 4;

    if (t < 16) sRows[t] = (t < nr) ? rows[c * CAP + rbase + t] : 0;

    // ---- Prefetch phase-1 (all 4) and phase-2 (first 6 chunks) b-fragments.
    //      These loads drain during the gather -> free overlap.
    const bf16x8* pb1 = (const bf16x8*)(p_state + (size_t)c * SD * 256);
    const bf16x8* pb2 = (const bf16x8*)p_obs;
    bf16x8 pf1[4], pf2[12];
    #pragma unroll
    for (int kk = 0; kk < 2; ++kk)
        #pragma unroll
        for (int si = 0; si < 2; ++si)
            pf1[kk * 2 + si] = pb1[(kk * 16 + w * 2 + si) * 64 + l];
    #pragma unroll
    for (int kk = 0; kk < 6; ++kk)
        #pragma unroll
        for (int si = 0; si < 2; ++si)
            pf2[kk * 2 + si] = pb2[(kk * 16 + w * 2 + si) * 64 + l];

    __syncthreads();   // sRows visible

    // Gather + fp32->bf16 (coalesced float4; rows >= nr zeroed)
    if (t < 256) {      // state: 16 rows x 64 = 256 float4 slots
        int i = t >> 4, c4 = t & 15;
        unsigned short vv[4] = {0, 0, 0, 0};
        if (i < nr) {
            float4 v = ((const float4*)(state + (size_t)sRows[i] * SD))[c4];
            vv[0] = bf_cvt(v.x); vv[1] = bf_cvt(v.y); vv[2] = bf_cvt(v.z); vv[3] = bf_cvt(v.w);
        }
        *(bf16x4*)&sAs[i * 72 + c4 * 4] = *(bf16x4*)vv;
    }
    #pragma unroll
    for (int i2 = 0; i2 < 4; ++i2) {         // obs: 16 rows x 512 = 2048 float4 slots
        int f = t + 512 * i2;
        int i = f >> 7, c4 = f & 127;
        unsigned short vv[4] = {0, 0, 0, 0};
        if (i < nr) {
            float4 v = ((const float4*)(obs + (size_t)sRows[i] * OBSD))[c4];
            vv[0] = bf_cvt(v.x); vv[1] = bf_cvt(v.y); vv[2] = bf_cvt(v.z); vv[3] = bf_cvt(v.w);
        }
        *(bf16x4*)&sAo[i * 520 + c4 * 4] = *(bf16x4*)vv;
    }
    __syncthreads();

    // ---- Phase 1: state_emb = relu(A_s x state_W[c] + b)  (K=64: 2 chunks) ----
    {
        f32x4 acc[2];
        #pragma unroll
        for (int si = 0; si < 2; ++si) acc[si] = (f32x4){0.f, 0.f, 0.f, 0.f};
        #pragma unroll
        for (int kk = 0; kk < 2; ++kk) {
            bf16x8 a = *(const bf16x8*)&sAs[ml * 72 + kk * 32 + quad * 8];
            #pragma unroll
            for (int si = 0; si < 2; ++si)
                acc[si] = __builtin_amdgcn_mfma_f32_16x16x32_bf16(a, pf1[kk * 2 + si], acc[si], 0, 0, 0);
        }
        #pragma unroll
        for (int si = 0; si < 2; ++si) {
            int colb = (w * 2 + si) * 16 + ml;
            float bias = state_b[c * 256 + colb];
            #pragma unroll
            for (int r = 0; r < 4; ++r)
                sX[(quad * 4 + r) * 520 + colb] = bf_cvt(fmaxf(acc[si][r] + bias, 0.f));
        }
    }

    // ---- Phase 2: obs_emb = A_o x obs_W + b  (K=512: 16 chunks, ring depth 6) ----
    {
        f32x4 acc[2];
        #pragma unroll
        for (int si = 0; si < 2; ++si) acc[si] = (f32x4){0.f, 0.f, 0.f, 0.f};
        #pragma unroll
        for (int kk = 0; kk < 16; ++kk) {
            bf16x8 a = *(const bf16x8*)&sAo[ml * 520 + kk * 32 + quad * 8];
            #pragma unroll
            for (int si = 0; si < 2; ++si) {
                int slot = (kk % 6) * 2 + si;
                bf16x8 b = pf2[slot];
                if (kk < 10)
                    pf2[slot] = pb2[((kk + 6) * 16 + w * 2 + si) * 64 + l];
                acc[si] = __builtin_amdgcn_mfma_f32_16x16x32_bf16(a, b, acc[si], 0, 0, 0);
            }
        }
        #pragma unroll
        for (int si = 0; si < 2; ++si) {
            int colb = (w * 2 + si) * 16 + ml;
            float bias = obs_b[colb];
            #pragma unroll
            for (int r = 0; r < 4; ++r)
                sX[(quad * 4 + r) * 520 + 256 + colb] = bf_cvt(acc[si][r] + bias);
        }
    }

    // ---- Prefetch phase-3 first 6 chunks BEFORE the sX barrier ----
    const bf16x8* pb3 = (const bf16x8*)p_l2 + (size_t)c * 16384;
    bf16x8 pf3[12];
    if (has_pl2) {
        #pragma unroll
        for (int kk = 0; kk < 6; ++kk)
            #pragma unroll
            for (int si = 0; si < 2; ++si)
                pf3[kk * 2 + si] = pb3[(kk * 16 + w * 2 + si) * 64 + l];
    }
    __syncthreads();

    // ---- Phase 3: out = x @ l2_W[c] + b  (K=512: 16 chunks, ring depth 6) ----
    {
        f32x4 acc[2];
        #pragma unroll
        for (int si = 0; si < 2; ++si) acc[si] = (f32x4){0.f, 0.f, 0.f, 0.f};
        if (has_pl2) {
            #pragma unroll
            for (int kk = 0; kk < 16; ++kk) {
                bf16x8 a = *(const bf16x8*)&sX[ml * 520 + kk * 32 + quad * 8];
                #pragma unroll
                for (int si = 0; si < 2; ++si) {
                    int slot = (kk % 6) * 2 + si;
                    bf16x8 b = pf3[slot];
                    if (kk < 10)
                        pf3[slot] = pb3[((kk + 6) * 16 + w * 2 + si) * 64 + l];
                    acc[si] = __builtin_amdgcn_mfma_f32_16x16x32_bf16(a, b, acc[si], 0, 0, 0);
                }
            }
        } else {
            for (int kk = 0; kk < 16; ++kk) {
                bf16x8 a = *(const bf16x8*)&sX[ml * 520 + kk * 32 + quad * 8];
                #pragma unroll
                for (int si = 0; si < 2; ++si) {
                    const float* wsrc = l2_W + ((size_t)c * XDIM + kk * 32 + quad * 8) * 256
                                        + (w * 2 + si) * 16 + ml;
                    bf16x8 b;
                    #pragma unroll
                    for (int j = 0; j < 8; ++j) b[j] = (short)bf_cvt(wsrc[j * 256]);
                    acc[si] = __builtin_amdgcn_mfma_f32_16x16x32_bf16(a, b, acc[si], 0, 0, 0);
                }
            }
        }
        #pragma unroll
        for (int si = 0; si < 2; ++si) {
            int colb = (w * 2 + si) * 16 + ml;
            float bias = l2_b[c * 256 + colb];
            #pragma unroll
            for (int r = 0; r < 4; ++r) {
                int row = quad * 4 + r;
                if (row < nr)
                    out[(size_t)sRows[row] * 256 + colb] = acc[si][r] + bias;
            }
        }
    }
}

extern "C" void kernel_launch(void* const* d_in, const int* in_sizes, int n_in,
                              void* d_out, int out_size, void* d_ws, size_t ws_size,
                              hipStream_t stream) {
    const float* state   = (const float*)d_in[0];
    const float* obs     = (const float*)d_in[1];
    const int*   cat_ids = (const int*)d_in[2];
    const float* obs_W   = (const float*)d_in[3];
    const float* obs_b   = (const float*)d_in[4];
    const float* state_W = (const float*)d_in[5];
    const float* state_b = (const float*)d_in[6];
    const float* l2_W    = (const float*)d_in[7];
    const float* l2_b    = (const float*)d_in[8];
    float* out = (float*)d_out;

    char* ws = (char*)d_ws;
    int* counts  = (int*)ws;
    int* rowsbuf = (int*)(ws + OFF_ROWS);
    unsigned short* p_obs  = (unsigned short*)(ws + OFF_POBS);
    unsigned short* p_stat = (unsigned short*)(ws + OFF_PSTAT);
    unsigned short* p_l2   = (unsigned short*)(ws + OFF_PL2);
    const int do_l2 = (ws_size >= NEED_L2) ? 1 : 0;

    int prep_blocks = C_N + 16 + 64 + (do_l2 ? 512 : 0);
    prep_kernel<<<dim3(prep_blocks), dim3(256), 0, stream>>>(
        cat_ids, obs_W, state_W, l2_W, counts, rowsbuf, p_obs, p_stat, p_l2, do_l2);

    fused_kernel<<<dim3(C_N, CAP / 16), dim3(512), 0, stream>>>(
        state, obs, obs_b, state_b, l2_W, l2_b, counts, rowsbuf,
        p_obs, p_stat, p_l2, do_l2, out);
}